// Round 5
// baseline (521.009 us; speedup 1.0000x reference)
//
#include <hip/hip_runtime.h>
#include <float.h>

#define BB 4
#define PP 1024
#define DD 1024
#define RR 256
#define SSZ 256
#define KT 4
#define EE 4096
#define NPAIR 3

// ---- workspace layout (float offsets) ----
#define OFF_REF_T  ((size_t)0)
#define OFF_REF_S  (OFF_REF_T + (size_t)BB*RR*DD)
#define OFF_RR_T   (OFF_REF_S + (size_t)BB*RR*DD)
#define OFF_RR_S   (OFF_RR_T + (size_t)BB*RR)
#define OFF_NE     (OFF_RR_S + (size_t)BB*RR)
#define OFF_SIM    (OFF_NE + (size_t)BB*EE)
#define OFF_TOPK   (OFF_SIM + (size_t)BB*RR*EE)
#define OFF_SIMH   (OFF_TOPK + (size_t)BB*RR*KT)
#define OFF_HH     (OFF_SIMH + (size_t)BB*RR*KT*DD)
#define OFF_RH_T   (OFF_HH + (size_t)BB*RR*KT)
#define OFF_RH_S   (OFF_RH_T + (size_t)BB*RR*KT)
#define OFF_SS_T   (OFF_RH_S + (size_t)BB*RR*KT)
#define OFF_SS_S   (OFF_SS_T + (size_t)NPAIR*BB*SSZ)
#define OFF_ACC    (OFF_SS_S + (size_t)NPAIR*BB*SSZ)   // double, even float offset

__device__ inline float block_sum256(float v, float* sb) {
  v += __shfl_down(v, 32); v += __shfl_down(v, 16);
  v += __shfl_down(v, 8);  v += __shfl_down(v, 4);
  v += __shfl_down(v, 2);  v += __shfl_down(v, 1);
  int lane = threadIdx.x & 63, wid = threadIdx.x >> 6;
  if (lane == 0) sb[wid] = v;
  __syncthreads();
  float r = 0.f;
  if (threadIdx.x < 4) r = sb[threadIdx.x];
  r += __shfl_down(r, 2); r += __shfl_down(r, 1);
  __syncthreads();
  return r;   // valid on thread 0
}

__device__ inline float dot4(const float4& a, const float4& b) {
  return a.x*b.x + a.y*b.y + a.z*b.z + a.w*b.w;
}

// ---- gather ref rows (teacher frame 0, student frame 0) + squared norms ----
__global__ __launch_bounds__(256) void k_gather_ref(const float* __restrict__ T,
                                                    const float* __restrict__ Sf,
                                                    const int* __restrict__ ref_perm,
                                                    float* __restrict__ ws) {
  __shared__ float sb[4];
  int b = blockIdx.x >> 8, r = blockIdx.x & 255;
  int pos = ref_perm[r];
  const float4* ts = (const float4*)(T  + ((size_t)(b*8 + 0)*PP + pos)*DD);
  const float4* sv = (const float4*)(Sf + ((size_t)(b*4 + 0)*PP + pos)*DD);
  float4* dt = (float4*)(ws + OFF_REF_T + ((size_t)b*RR + r)*DD);
  float4* ds = (float4*)(ws + OFF_REF_S + ((size_t)b*RR + r)*DD);
  int t = threadIdx.x;                    // DD/4 == 256
  float4 a = ts[t], c = sv[t];
  dt[t] = a; ds[t] = c;
  float r1 = block_sum256(dot4(a, a), sb);
  float r2 = block_sum256(dot4(c, c), sb);
  if (threadIdx.x == 0) {
    ws[OFF_RR_T + b*RR + r] = r1;
    ws[OFF_RR_S + b*RR + r] = r2;
  }
}

// ---- clamped norms of extra_t rows ----
__global__ __launch_bounds__(256) void k_ne(const float* __restrict__ T, float* __restrict__ ws) {
  __shared__ float sb[4];
  int b = blockIdx.x >> 12, e = blockIdx.x & 4095;
  int f = 1 + 2*(e >> 10);
  int pos = e & 1023;
  const float4* src = (const float4*)(T + ((size_t)(b*8 + f)*PP + pos)*DD);
  float4 a = src[threadIdx.x];
  float tot = block_sum256(dot4(a, a), sb);
  if (threadIdx.x == 0) ws[OFF_NE + (size_t)b*EE + e] = fmaxf(sqrtf(tot), 1e-12f);
}

// ---- squared norms of shared rows (teacher + student), all 3 pairs ----
__global__ __launch_bounds__(256) void k_ss(const float* __restrict__ T,
                                            const float* __restrict__ Sf,
                                            const int* __restrict__ shared_perm,
                                            float* __restrict__ ws) {
  __shared__ float sb[4];
  int idx = blockIdx.x;                  // p*BB*SSZ + b*SSZ + s
  int p = idx / (BB*SSZ);
  int b = (idx / SSZ) % BB;
  int s = idx % SSZ;
  int pos = shared_perm[s];
  int ti = 2*(p + 1), si = p + 1;
  const float4* tr = (const float4*)(T  + ((size_t)(b*8 + ti)*PP + pos)*DD);
  const float4* sr = (const float4*)(Sf + ((size_t)(b*4 + si)*PP + pos)*DD);
  float4 a = tr[threadIdx.x], c = sr[threadIdx.x];
  float r1 = block_sum256(dot4(a, a), sb);
  float r2 = block_sum256(dot4(c, c), sb);
  if (threadIdx.x == 0) { ws[OFF_SS_T + idx] = r1; ws[OFF_SS_S + idx] = r2; }
}

// ---- sim GEMM: sim[b,r,e] = (ref_t[b,r] . extra[b,e]) / ne[b,e] (ranking only) ----
__global__ __launch_bounds__(256) void k_sim(const float* __restrict__ T, float* __restrict__ ws) {
  __shared__ float As[16][68];
  __shared__ float Bs[16][68];
  int e0 = blockIdx.x * 64;
  int r0 = blockIdx.y * 64;
  int b  = blockIdx.z;
  int tid = threadIdx.x;
  int lr = tid >> 2;                 // 0..63 : load row
  int lc = (tid & 3) * 4;            // 0,4,8,12
  const float* pA = ws + OFF_REF_T + ((size_t)b*RR + r0 + lr)*DD + lc;
  int e = e0 + lr;
  const float* pB = T + ((size_t)(b*8 + 1 + 2*(e >> 10))*PP + (e & 1023))*DD + lc;
  int ty = tid >> 4, tx = tid & 15;
  float acc[4][4] = {};
  for (int k0 = 0; k0 < DD; k0 += 16) {
    float4 av = *(const float4*)(pA + k0);
    float4 bv = *(const float4*)(pB + k0);
    As[lc+0][lr] = av.x; As[lc+1][lr] = av.y; As[lc+2][lr] = av.z; As[lc+3][lr] = av.w;
    Bs[lc+0][lr] = bv.x; Bs[lc+1][lr] = bv.y; Bs[lc+2][lr] = bv.z; Bs[lc+3][lr] = bv.w;
    __syncthreads();
#pragma unroll
    for (int kk = 0; kk < 16; ++kk) {
      const float4 a4 = *(const float4*)&As[kk][ty*4];
      const float4 b4 = *(const float4*)&Bs[kk][tx*4];
      float aa[4] = {a4.x, a4.y, a4.z, a4.w};
      float bb[4] = {b4.x, b4.y, b4.z, b4.w};
#pragma unroll
      for (int i = 0; i < 4; ++i)
#pragma unroll
        for (int j = 0; j < 4; ++j) acc[i][j] = fmaf(aa[i], bb[j], acc[i][j]);
    }
    __syncthreads();
  }
  const float4 nv = *(const float4*)(ws + OFF_NE + (size_t)b*EE + e0 + tx*4);
  float inv[4] = {1.f/nv.x, 1.f/nv.y, 1.f/nv.z, 1.f/nv.w};
#pragma unroll
  for (int i = 0; i < 4; ++i) {
    float4 o;
    o.x = acc[i][0]*inv[0]; o.y = acc[i][1]*inv[1];
    o.z = acc[i][2]*inv[2]; o.w = acc[i][3]*inv[3];
    *(float4*)(ws + OFF_SIM + ((size_t)b*RR + r0 + ty*4 + i)*EE + e0 + tx*4) = o;
  }
}

// ---- top-4 per (b,r), stable (ties -> lower index) ----
__global__ __launch_bounds__(256) void k_topk(float* __restrict__ ws) {
  __shared__ float vals[EE];
  __shared__ float rv[256];
  __shared__ int   ri[256];
  int b = blockIdx.x >> 8, r = blockIdx.x & 255;
  const float* srow = ws + OFF_SIM + ((size_t)b*RR + r)*EE;
  int tid = threadIdx.x;
#pragma unroll
  for (int i = 0; i < 16; ++i) vals[i*256 + tid] = srow[i*256 + tid];
  __syncthreads();
  int* outi = (int*)(ws + OFF_TOPK) + ((size_t)b*RR + r)*KT;
  for (int k = 0; k < KT; ++k) {
    float bv = -FLT_MAX; int bi = 0x7fffffff;
#pragma unroll
    for (int i = 0; i < 16; ++i) {
      int e = i*256 + tid;
      float v = vals[e];
      if (v > bv || (v == bv && e < bi)) { bv = v; bi = e; }
    }
    rv[tid] = bv; ri[tid] = bi;
    __syncthreads();
    for (int off = 128; off > 0; off >>= 1) {
      if (tid < off) {
        float v2 = rv[tid+off]; int i2 = ri[tid+off];
        if (v2 > rv[tid] || (v2 == rv[tid] && i2 < ri[tid])) { rv[tid] = v2; ri[tid] = i2; }
      }
      __syncthreads();
    }
    if (tid == 0) { outi[k] = ri[0]; vals[ri[0]] = -FLT_MAX; }
    __syncthreads();
  }
}

// ---- gather selected rows + hh / rh_t / rh_s ----
__global__ __launch_bounds__(256) void k_gather_high(const float* __restrict__ T,
                                                     float* __restrict__ ws) {
  __shared__ float sb[4];
  int idx = blockIdx.x;                        // (b*RR + r)*KT + k
  int e = ((const int*)(ws + OFF_TOPK))[idx];
  int b = idx >> 10;
  int br = idx >> 2;                           // b*RR + r
  const float4* src = (const float4*)(T + ((size_t)(b*8 + 1 + 2*(e >> 10))*PP + (e & 1023))*DD);
  float4* dst = (float4*)(ws + OFF_SIMH + (size_t)idx*DD);
  const float4* rt = (const float4*)(ws + OFF_REF_T + (size_t)br*DD);
  const float4* rs = (const float4*)(ws + OFF_REF_S + (size_t)br*DD);
  int t = threadIdx.x;
  float4 h = src[t]; dst[t] = h;
  float4 a = rt[t], c = rs[t];
  float r1 = block_sum256(dot4(h, h), sb);
  float r2 = block_sum256(dot4(h, a), sb);
  float r3 = block_sum256(dot4(h, c), sb);
  if (t == 0) { ws[OFF_HH + idx] = r1; ws[OFF_RH_T + idx] = r2; ws[OFF_RH_S + idx] = r3; }
}

// ---- main fused kernel: sh/sr GEMM + cosine epilogue + reduction ----
// A rows (192): [0..127] sim_high(rl,k), [128..159] ref_t(rl), [160..191] ref_s(rl)
// B cols (64) : [0..31] sh_t(sl), [32..63] sh_s(sl)
__global__ __launch_bounds__(256) void k_main(const float* __restrict__ T,
                                              const float* __restrict__ Sf,
                                              const int* __restrict__ shared_perm,
                                              float* __restrict__ ws,
                                              double* __restrict__ acc_out) {
  __shared__ union SM {
    struct { float As[16][200]; float Bs[16][68]; } ab;
    float Cs[192][65];
  } sm;
  __shared__ float sb[4];

  int s0 = blockIdx.x * 32;
  int r0 = blockIdx.y * 32;
  int z  = blockIdx.z;                 // p*4 + b
  int p = z >> 2, b = z & 3;
  int ti = 2*(p + 1), si = p + 1;
  int tid = threadIdx.x;
  int lrow = tid >> 2;                 // 0..63
  int lc4 = (tid & 3) * 4;             // 0,4,8,12

  const float* pA0; const float* pA1; const float* pA2;
  {
    int a0 = lrow;                     // 0..63  -> sim_high rl 0..15
    pA0 = ws + OFF_SIMH + (((size_t)b*RR + r0 + (a0 >> 2))*KT + (a0 & 3))*DD + lc4;
    int a1 = lrow + 64;                // 64..127 -> sim_high rl 16..31
    pA1 = ws + OFF_SIMH + (((size_t)b*RR + r0 + (a1 >> 2))*KT + (a1 & 3))*DD + lc4;
    int a2 = lrow + 128;               // 128..191
    if (a2 < 160) pA2 = ws + OFF_REF_T + ((size_t)b*RR + r0 + (a2 - 128))*DD + lc4;
    else          pA2 = ws + OFF_REF_S + ((size_t)b*RR + r0 + (a2 - 160))*DD + lc4;
  }
  const float* pB;
  {
    int c = lrow;                      // 0..63
    int sl = (c < 32) ? c : (c - 32);
    int pos = shared_perm[s0 + sl];
    pB = (c < 32) ? (T  + ((size_t)(b*8 + ti)*PP + pos)*DD + lc4)
                  : (Sf + ((size_t)(b*4 + si)*PP + pos)*DD + lc4);
  }

  int ty = tid >> 4;                   // rows ty*12..+11
  int tx = tid & 15;                   // cols tx*4..+3
  float acc[12][4] = {};

  for (int k0 = 0; k0 < DD; k0 += 16) {
    float4 a0 = *(const float4*)(pA0 + k0);
    float4 a1 = *(const float4*)(pA1 + k0);
    float4 a2 = *(const float4*)(pA2 + k0);
    float4 bv = *(const float4*)(pB + k0);
    sm.ab.As[lc4+0][lrow      ] = a0.x; sm.ab.As[lc4+1][lrow      ] = a0.y;
    sm.ab.As[lc4+2][lrow      ] = a0.z; sm.ab.As[lc4+3][lrow      ] = a0.w;
    sm.ab.As[lc4+0][lrow + 64 ] = a1.x; sm.ab.As[lc4+1][lrow + 64 ] = a1.y;
    sm.ab.As[lc4+2][lrow + 64 ] = a1.z; sm.ab.As[lc4+3][lrow + 64 ] = a1.w;
    sm.ab.As[lc4+0][lrow + 128] = a2.x; sm.ab.As[lc4+1][lrow + 128] = a2.y;
    sm.ab.As[lc4+2][lrow + 128] = a2.z; sm.ab.As[lc4+3][lrow + 128] = a2.w;
    sm.ab.Bs[lc4+0][lrow] = bv.x; sm.ab.Bs[lc4+1][lrow] = bv.y;
    sm.ab.Bs[lc4+2][lrow] = bv.z; sm.ab.Bs[lc4+3][lrow] = bv.w;
    __syncthreads();
#pragma unroll
    for (int kk = 0; kk < 16; ++kk) {
      const float4 b4  = *(const float4*)&sm.ab.Bs[kk][tx*4];
      const float4 av0 = *(const float4*)&sm.ab.As[kk][ty*12];
      const float4 av1 = *(const float4*)&sm.ab.As[kk][ty*12 + 4];
      const float4 av2 = *(const float4*)&sm.ab.As[kk][ty*12 + 8];
      float aa[12] = {av0.x, av0.y, av0.z, av0.w, av1.x, av1.y, av1.z, av1.w,
                      av2.x, av2.y, av2.z, av2.w};
      float bb[4] = {b4.x, b4.y, b4.z, b4.w};
#pragma unroll
      for (int i = 0; i < 12; ++i)
#pragma unroll
        for (int j = 0; j < 4; ++j) acc[i][j] = fmaf(aa[i], bb[j], acc[i][j]);
    }
    __syncthreads();
  }

  // C -> LDS (union: As/Bs no longer needed; barrier above guarantees safety)
#pragma unroll
  for (int i = 0; i < 12; ++i)
#pragma unroll
    for (int j = 0; j < 4; ++j) sm.Cs[ty*12 + i][tx*4 + j] = acc[i][j];
  __syncthreads();

  // epilogue: thread -> (rl = tid>>3, sg = tid&7 -> 4 s values), k = 0..3
  int rl = tid >> 3;
  int sg = tid & 7;
  int r = r0 + rl;
  float rrt = ws[OFF_RR_T + b*RR + r];
  float rrs = ws[OFF_RR_S + b*RR + r];
  float hhk[4], rhtk[4], rhsk[4], ihr_t[4], ihr_s[4];
#pragma unroll
  for (int k = 0; k < 4; ++k) {
    int idx = (b*RR + r)*KT + k;
    hhk[k]  = ws[OFF_HH + idx];
    rhtk[k] = ws[OFF_RH_T + idx];
    rhsk[k] = ws[OFF_RH_S + idx];
    float nt = sqrtf(fmaxf(hhk[k] - 2.f*rhtk[k] + rrt, 0.f));
    float ns = sqrtf(fmaxf(hhk[k] - 2.f*rhsk[k] + rrs, 0.f));
    ihr_t[k] = 1.f / fmaxf(nt, 1e-8f);
    ihr_s[k] = 1.f / fmaxf(ns, 1e-8f);
  }
  float local = 0.f;
#pragma unroll
  for (int j = 0; j < 4; ++j) {
    int sl = sg*4 + j;
    int sidx = (p*BB + b)*SSZ + (s0 + sl);
    float sst = ws[OFF_SS_T + sidx];
    float sss = ws[OFF_SS_S + sidx];
    float srt = sm.Cs[128 + rl][sl];
    float srs = sm.Cs[160 + rl][32 + sl];
    float isr_t = 1.f / fmaxf(sqrtf(fmaxf(sst - 2.f*srt + rrt, 0.f)), 1e-8f);
    float isr_s = 1.f / fmaxf(sqrtf(fmaxf(sss - 2.f*srs + rrs, 0.f)), 1e-8f);
#pragma unroll
    for (int k = 0; k < 4; ++k) {
      float sht = sm.Cs[rl*4 + k][sl];
      float shs = sm.Cs[rl*4 + k][32 + sl];
      float ish_t = 1.f / fmaxf(sqrtf(fmaxf(sst - 2.f*sht + hhk[k], 0.f)), 1e-8f);
      float ish_s = 1.f / fmaxf(sqrtf(fmaxf(sss - 2.f*shs + hhk[k], 0.f)), 1e-8f);
      float a1t = (sht - rhtk[k] - srt + rrt) * (isr_t * ihr_t[k]);
      float a2t = (srt - sht - rhtk[k] + hhk[k]) * (ihr_t[k] * ish_t);
      float a3t = (rhtk[k] - srt - sht + sst) * (isr_t * ish_t);
      float a1s = (shs - rhsk[k] - srs + rrs) * (isr_s * ihr_s[k]);
      float a2s = (srs - shs - rhsk[k] + hhk[k]) * (ihr_s[k] * ish_s);
      float a3s = (rhsk[k] - srs - shs + sss) * (isr_s * ish_s);
      local += fabsf(a1s - a1t) + fabsf(a2s - a2t) + fabsf(a3s - a3t);
    }
  }
  float tot = block_sum256(local, sb);
  if (tid == 0) atomicAdd(acc_out, (double)tot);
}

__global__ void k_final(const double* __restrict__ acc, float* __restrict__ out) {
  out[0] = (float)(acc[0] / 3145728.0);   // 3 * B * R * S * K
}

extern "C" void kernel_launch(void* const* d_in, const int* in_sizes, int n_in,
                              void* d_out, int out_size, void* d_ws, size_t ws_size,
                              hipStream_t stream) {
  const float* T  = (const float*)d_in[0];
  const float* Sf = (const float*)d_in[1];
  const int* ref_perm    = (const int*)d_in[2];
  const int* shared_perm = (const int*)d_in[3];
  float* ws = (float*)d_ws;
  double* acc = (double*)(ws + OFF_ACC);

  hipMemsetAsync(acc, 0, sizeof(double), stream);
  k_gather_ref<<<BB*RR, 256, 0, stream>>>(T, Sf, ref_perm, ws);
  k_ne<<<BB*EE, 256, 0, stream>>>(T, ws);
  k_ss<<<NPAIR*BB*SSZ, 256, 0, stream>>>(T, Sf, shared_perm, ws);
  dim3 g1(EE/64, RR/64, BB);
  k_sim<<<g1, 256, 0, stream>>>(T, ws);
  k_topk<<<BB*RR, 256, 0, stream>>>(ws);
  k_gather_high<<<BB*RR*KT, 256, 0, stream>>>(T, ws);
  dim3 g2(SSZ/32, RR/32, NPAIR*BB);
  k_main<<<g2, 256, 0, stream>>>(T, Sf, shared_perm, ws, acc);
  k_final<<<1, 1, 0, stream>>>(acc, (float*)d_out);
}

// Round 7
// 258.125 us; speedup vs baseline: 2.0184x; 2.0184x over previous
//
#include <hip/hip_runtime.h>
#include <float.h>

#define BB 4
#define PP 1024
#define DD 1024
#define RR 256
#define SSZ 256
#define KT 4
#define EE 4096
#define NPAIR 3

typedef float  f32x4  __attribute__((ext_vector_type(4)));
typedef short  short8 __attribute__((ext_vector_type(8)));

#define MFMA16(a,b,c) __builtin_amdgcn_mfma_f32_16x16x32_bf16((a),(b),(c),0,0,0)

// ---- float-region offsets (in floats) ----
#define OFF_NE    ((size_t)0)         // BB*EE
#define OFF_RR_T  ((size_t)16384)     // BB*RR
#define OFF_RR_S  ((size_t)17408)
#define OFF_HH    ((size_t)18432)     // BB*RR*KT
#define OFF_RH_T  ((size_t)22528)
#define OFF_RH_S  ((size_t)26624)
#define OFF_SS_T  ((size_t)30720)     // NPAIR*BB*SSZ
#define OFF_SS_S  ((size_t)33792)
#define OFF_TOPK  ((size_t)36864)     // BB*RR*KT ints
#define OFF_ACC   ((size_t)40960)     // double (8B aligned)
#define OFF_SIM   ((size_t)45056)     // BB*RR*EE floats (16B aligned)
#define FLOAT_END ((size_t)4239360)   // = OFF_SIM + 4194304

// ---- ushort (bf16) region offsets (in ushorts), base = ws + FLOAT_END ----
#define U_REF_T_HI ((size_t)0)        // BB*RR*DD
#define U_REF_S_HI ((size_t)2097152)
#define U_SIMH_HI  ((size_t)4194304)  // BB*RR*KT*DD
#define REF_DELTA  ((size_t)1048576)  // hi -> lo distance for ref arrays
#define SIMH_DELTA ((size_t)4194304)  // hi -> lo distance for simh

__device__ inline float block_sum256(float v, float* sb) {
  v += __shfl_down(v, 32); v += __shfl_down(v, 16);
  v += __shfl_down(v, 8);  v += __shfl_down(v, 4);
  v += __shfl_down(v, 2);  v += __shfl_down(v, 1);
  int lane = threadIdx.x & 63, wid = threadIdx.x >> 6;
  if (lane == 0) sb[wid] = v;
  __syncthreads();
  float r = 0.f;
  if (threadIdx.x < 4) r = sb[threadIdx.x];
  r += __shfl_down(r, 2); r += __shfl_down(r, 1);
  __syncthreads();
  return r;   // valid on thread 0
}

__device__ inline float dot4(const float4& a, const float4& b) {
  return a.x*b.x + a.y*b.y + a.z*b.z + a.w*b.w;
}

// round-to-nearest-even split: x = hi + lo (both bf16), |err| ~ 2^-16 |x|
__device__ inline ushort2 bsplit(float x) {
  unsigned u = __float_as_uint(x);
  unsigned hb = (u + 0x7fffu + ((u >> 16) & 1u)) & 0xffff0000u;
  float lo = x - __uint_as_float(hb);
  unsigned ul = __float_as_uint(lo);
  unsigned lb = (ul + 0x7fffu + ((ul >> 16) & 1u)) >> 16;
  return make_ushort2((unsigned short)(hb >> 16), (unsigned short)lb);
}

__device__ inline void split4(float4 f, ushort4& h, ushort4& l) {
  ushort2 t0 = bsplit(f.x), t1 = bsplit(f.y), t2 = bsplit(f.z), t3 = bsplit(f.w);
  h = make_ushort4(t0.x, t1.x, t2.x, t3.x);
  l = make_ushort4(t0.y, t1.y, t2.y, t3.y);
}

__device__ inline void split8(const float* p, uint4& h, uint4& l) {
  float4 f0 = *(const float4*)p;
  float4 f1 = *(const float4*)(p + 4);
  ushort2 t0 = bsplit(f0.x), t1 = bsplit(f0.y), t2 = bsplit(f0.z), t3 = bsplit(f0.w);
  ushort2 t4 = bsplit(f1.x), t5 = bsplit(f1.y), t6 = bsplit(f1.z), t7 = bsplit(f1.w);
  h.x = (unsigned)t0.x | ((unsigned)t1.x << 16); h.y = (unsigned)t2.x | ((unsigned)t3.x << 16);
  h.z = (unsigned)t4.x | ((unsigned)t5.x << 16); h.w = (unsigned)t6.x | ((unsigned)t7.x << 16);
  l.x = (unsigned)t0.y | ((unsigned)t1.y << 16); l.y = (unsigned)t2.y | ((unsigned)t3.y << 16);
  l.z = (unsigned)t4.y | ((unsigned)t5.y << 16); l.w = (unsigned)t6.y | ((unsigned)t7.y << 16);
}

// ---- gather ref rows: norms + bf16 hi/lo split store ----
__global__ __launch_bounds__(256) void k_gather_ref(const float* __restrict__ T,
                                                    const float* __restrict__ Sf,
                                                    const int* __restrict__ ref_perm,
                                                    float* __restrict__ ws) {
  __shared__ float sb[4];
  int b = blockIdx.x >> 8, r = blockIdx.x & 255;
  int pos = ref_perm[r];
  const float4* ts = (const float4*)(T  + ((size_t)(b*8 + 0)*PP + pos)*DD);
  const float4* sv = (const float4*)(Sf + ((size_t)(b*4 + 0)*PP + pos)*DD);
  ushort* uws = (ushort*)(ws + FLOAT_END);
  int t = threadIdx.x;                    // DD/4 == 256
  float4 a = ts[t], c = sv[t];
  size_t base = ((size_t)b*RR + r)*DD + t*4;
  ushort4 h4, l4;
  split4(a, h4, l4);
  *(ushort4*)(uws + U_REF_T_HI + base) = h4;
  *(ushort4*)(uws + U_REF_T_HI + REF_DELTA + base) = l4;
  split4(c, h4, l4);
  *(ushort4*)(uws + U_REF_S_HI + base) = h4;
  *(ushort4*)(uws + U_REF_S_HI + REF_DELTA + base) = l4;
  float r1 = block_sum256(dot4(a, a), sb);
  float r2 = block_sum256(dot4(c, c), sb);
  if (t == 0) {
    ws[OFF_RR_T + b*RR + r] = r1;
    ws[OFF_RR_S + b*RR + r] = r2;
  }
}

// ---- clamped norms of extra_t rows ----
__global__ __launch_bounds__(256) void k_ne(const float* __restrict__ T, float* __restrict__ ws) {
  __shared__ float sb[4];
  int b = blockIdx.x >> 12, e = blockIdx.x & 4095;
  int f = 1 + 2*(e >> 10);
  int pos = e & 1023;
  const float4* src = (const float4*)(T + ((size_t)(b*8 + f)*PP + pos)*DD);
  float4 a = src[threadIdx.x];
  float tot = block_sum256(dot4(a, a), sb);
  if (threadIdx.x == 0) ws[OFF_NE + (size_t)b*EE + e] = fmaxf(sqrtf(tot), 1e-12f);
}

// ---- squared norms of shared rows (teacher + student), all 3 pairs ----
__global__ __launch_bounds__(256) void k_ss(const float* __restrict__ T,
                                            const float* __restrict__ Sf,
                                            const int* __restrict__ shared_perm,
                                            float* __restrict__ ws) {
  __shared__ float sb[4];
  int idx = blockIdx.x;                  // p*BB*SSZ + b*SSZ + s
  int p = idx / (BB*SSZ);
  int b = (idx / SSZ) % BB;
  int s = idx % SSZ;
  int pos = shared_perm[s];
  int ti = 2*(p + 1), si = p + 1;
  const float4* tr = (const float4*)(T  + ((size_t)(b*8 + ti)*PP + pos)*DD);
  const float4* sr = (const float4*)(Sf + ((size_t)(b*4 + si)*PP + pos)*DD);
  float4 a = tr[threadIdx.x], c = sr[threadIdx.x];
  float r1 = block_sum256(dot4(a, a), sb);
  float r2 = block_sum256(dot4(c, c), sb);
  if (threadIdx.x == 0) { ws[OFF_SS_T + idx] = r1; ws[OFF_SS_S + idx] = r2; }
}

// ---- sim GEMM (MFMA bf16 hi/lo): sim[b,r,e] = dot(ref_t, extra_e)/ne[e] ----
// 64x64 tile, BK=32. 4 waves; wave w -> rows [w*16, w*16+16), all 4 col-frags.
__global__ __launch_bounds__(256) void k_sim(const float* __restrict__ T, float* __restrict__ ws) {
  __shared__ ushort Ah[64][40];
  __shared__ ushort Al[64][40];
  __shared__ ushort Bh[64][40];
  __shared__ ushort Bl[64][40];
  ushort* uws = (ushort*)(ws + FLOAT_END);
  int e0 = blockIdx.x * 64, r0 = blockIdx.y * 64, b = blockIdx.z;
  int tid = threadIdx.x;
  int srow = tid >> 2, sch = tid & 3;
  const ushort* pAh = uws + U_REF_T_HI + ((size_t)(b*RR + r0 + srow))*DD + sch*8;
  int e = e0 + srow;
  const float* pB = T + ((size_t)(b*8 + 1 + 2*(e >> 10))*PP + (e & 1023))*DD + sch*8;
  int w = tid >> 6, l15 = tid & 15, lq = (tid >> 4) & 3, lk8 = lq*8;
  f32x4 acc[4];
#pragma unroll
  for (int j = 0; j < 4; ++j) acc[j] = (f32x4){0.f, 0.f, 0.f, 0.f};

#pragma unroll 1
  for (int k0 = 0; k0 < DD; k0 += 32) {
    uint4 vah = *(const uint4*)(pAh + k0);
    uint4 valo = *(const uint4*)(pAh + REF_DELTA + k0);
    uint4 bhv, blv;
    split8(pB + k0, bhv, blv);
    __syncthreads();
    *(uint4*)&Ah[srow][sch*8] = vah;
    *(uint4*)&Al[srow][sch*8] = valo;
    *(uint4*)&Bh[srow][sch*8] = bhv;
    *(uint4*)&Bl[srow][sch*8] = blv;
    __syncthreads();
    short8 ah = *(const short8*)&Ah[w*16 + l15][lk8];
    short8 al = *(const short8*)&Al[w*16 + l15][lk8];
#pragma unroll
    for (int j = 0; j < 4; ++j) {
      short8 bh = *(const short8*)&Bh[j*16 + l15][lk8];
      short8 bl = *(const short8*)&Bl[j*16 + l15][lk8];
      acc[j] = MFMA16(ah, bh, acc[j]);
      acc[j] = MFMA16(ah, bl, acc[j]);
      acc[j] = MFMA16(al, bh, acc[j]);
    }
  }
#pragma unroll
  for (int j = 0; j < 4; ++j) {
    int ee = e0 + j*16 + l15;
    float inv = 1.f / ws[OFF_NE + (size_t)b*EE + ee];
#pragma unroll
    for (int q = 0; q < 4; ++q) {
      int row = r0 + w*16 + lq*4 + q;
      ws[OFF_SIM + ((size_t)(b*RR + row) << 12) + ee] = acc[j][q] * inv;
    }
  }
}

// ---- top-4 per (b,r), stable (ties -> lower index) ----
__global__ __launch_bounds__(256) void k_topk(float* __restrict__ ws) {
  __shared__ float vals[EE];
  __shared__ float rv[256];
  __shared__ int   ri[256];
  int b = blockIdx.x >> 8, r = blockIdx.x & 255;
  const float* srow = ws + OFF_SIM + ((size_t)(b*RR + r))*EE;
  int tid = threadIdx.x;
#pragma unroll
  for (int i = 0; i < 16; ++i) vals[i*256 + tid] = srow[i*256 + tid];
  __syncthreads();
  int* outi = (int*)(ws + OFF_TOPK) + ((size_t)(b*RR + r))*KT;
  for (int k = 0; k < KT; ++k) {
    float bv = -FLT_MAX; int bi = 0x7fffffff;
#pragma unroll
    for (int i = 0; i < 16; ++i) {
      int e = i*256 + tid;
      float v = vals[e];
      if (v > bv || (v == bv && e < bi)) { bv = v; bi = e; }
    }
    rv[tid] = bv; ri[tid] = bi;
    __syncthreads();
    for (int off = 128; off > 0; off >>= 1) {
      if (tid < off) {
        float v2 = rv[tid+off]; int i2 = ri[tid+off];
        if (v2 > rv[tid] || (v2 == rv[tid] && i2 < ri[tid])) { rv[tid] = v2; ri[tid] = i2; }
      }
      __syncthreads();
    }
    if (tid == 0) { outi[k] = ri[0]; vals[ri[0]] = -FLT_MAX; }
    __syncthreads();
  }
}

// ---- gather selected rows: bf16 hi/lo store + hh / rh_t / rh_s (fp32) ----
__global__ __launch_bounds__(256) void k_gather_high(const float* __restrict__ T,
                                                     const float* __restrict__ Sf,
                                                     const int* __restrict__ ref_perm,
                                                     float* __restrict__ ws) {
  __shared__ float sb[4];
  int idx = blockIdx.x;                        // (b*RR + r)*KT + k
  int e = ((const int*)(ws + OFF_TOPK))[idx];
  int b = idx >> 10;
  int r = (idx >> 2) & 255;
  int rpos = ref_perm[r];
  const float4* src = (const float4*)(T + ((size_t)(b*8 + 1 + 2*(e >> 10))*PP + (e & 1023))*DD);
  const float4* rt  = (const float4*)(T  + ((size_t)(b*8 + 0)*PP + rpos)*DD);
  const float4* rs  = (const float4*)(Sf + ((size_t)(b*4 + 0)*PP + rpos)*DD);
  ushort* uws = (ushort*)(ws + FLOAT_END);
  int t = threadIdx.x;
  float4 h = src[t];
  ushort4 h4, l4;
  split4(h, h4, l4);
  *(ushort4*)(uws + U_SIMH_HI + (size_t)idx*DD + t*4) = h4;
  *(ushort4*)(uws + U_SIMH_HI + SIMH_DELTA + (size_t)idx*DD + t*4) = l4;
  float4 a = rt[t], c = rs[t];
  float r1 = block_sum256(dot4(h, h), sb);
  float r2 = block_sum256(dot4(h, a), sb);
  float r3 = block_sum256(dot4(h, c), sb);
  if (t == 0) { ws[OFF_HH + idx] = r1; ws[OFF_RH_T + idx] = r2; ws[OFF_RH_S + idx] = r3; }
}

// ---- main fused kernel: MFMA hi/lo GEMM + cosine epilogue + reduction ----
// A rows (192): [0..127] sim_high(rl,k), [128..159] ref_t, [160..191] ref_s
// B cols (64) : [0..31] sh_t(sl), [32..63] sh_s(sl).  BK=32, 4 waves x 3 rowfrags x 4 colfrags.
__global__ __launch_bounds__(256) void k_main(const float* __restrict__ T,
                                              const float* __restrict__ Sf,
                                              const int* __restrict__ shared_perm,
                                              float* __restrict__ ws,
                                              double* __restrict__ acc_out) {
  __shared__ union SM {
    struct { ushort Ah[192][40]; ushort Al[192][40]; ushort Bh[64][40]; ushort Bl[64][40]; } ab;
    float Cs[192][65];
  } sm;
  __shared__ float sb[4];
  ushort* uws = (ushort*)(ws + FLOAT_END);

  int s0 = blockIdx.x * 32;
  int r0 = blockIdx.y * 32;
  int z  = blockIdx.z;                 // p*4 + b
  int p = z >> 2, b = z & 3;
  int ti = 2*(p + 1), si = p + 1;
  int tid = threadIdx.x;
  int srow = tid >> 2, sch = tid & 3;  // staging: row 0..63, 16B chunk 0..3

  // A-side sources (bf16 hi, lo at +delta)
  size_t row0 = ((size_t)(b*RR + r0) + (srow >> 2))*KT + (srow & 3);   // sim_high rows 0..63
  const ushort* pa0 = uws + U_SIMH_HI + row0*DD + sch*8;
  const ushort* pa1 = pa0 + (size_t)64*DD;                             // rows 64..127 (+16 in r)
  const ushort* pa2 = (srow < 32)
      ? (uws + U_REF_T_HI + ((size_t)(b*RR + r0 + srow))*DD + sch*8)
      : (uws + U_REF_S_HI + ((size_t)(b*RR + r0 + srow - 32))*DD + sch*8);
  // B-side source (fp32, split in-kernel)
  int c = srow;
  int sl = (c < 32) ? c : (c - 32);
  int pos = shared_perm[s0 + sl];
  const float* pB = (c < 32) ? (T  + ((size_t)(b*8 + ti)*PP + pos)*DD + sch*8)
                             : (Sf + ((size_t)(b*4 + si)*PP + pos)*DD + sch*8);

  int w = tid >> 6, l15 = tid & 15, lq = (tid >> 4) & 3, lk8 = lq*8;
  f32x4 acc[3][4];
#pragma unroll
  for (int i = 0; i < 3; ++i)
#pragma unroll
    for (int j = 0; j < 4; ++j) acc[i][j] = (f32x4){0.f, 0.f, 0.f, 0.f};

#pragma unroll 1
  for (int k0 = 0; k0 < DD; k0 += 32) {
    uint4 a0h = *(const uint4*)(pa0 + k0);
    uint4 a0l = *(const uint4*)(pa0 + SIMH_DELTA + k0);
    uint4 a1h = *(const uint4*)(pa1 + k0);
    uint4 a1l = *(const uint4*)(pa1 + SIMH_DELTA + k0);
    uint4 a2h = *(const uint4*)(pa2 + k0);
    uint4 a2l = *(const uint4*)(pa2 + REF_DELTA + k0);
    uint4 bhv, blv;
    split8(pB + k0, bhv, blv);
    __syncthreads();
    *(uint4*)&sm.ab.Ah[srow      ][sch*8] = a0h;
    *(uint4*)&sm.ab.Al[srow      ][sch*8] = a0l;
    *(uint4*)&sm.ab.Ah[ 64 + srow][sch*8] = a1h;
    *(uint4*)&sm.ab.Al[ 64 + srow][sch*8] = a1l;
    *(uint4*)&sm.ab.Ah[128 + srow][sch*8] = a2h;
    *(uint4*)&sm.ab.Al[128 + srow][sch*8] = a2l;
    *(uint4*)&sm.ab.Bh[srow][sch*8] = bhv;
    *(uint4*)&sm.ab.Bl[srow][sch*8] = blv;
    __syncthreads();
    short8 ah[3], al[3];
#pragma unroll
    for (int i = 0; i < 3; ++i) {
      ah[i] = *(const short8*)&sm.ab.Ah[(3*w + i)*16 + l15][lk8];
      al[i] = *(const short8*)&sm.ab.Al[(3*w + i)*16 + l15][lk8];
    }
#pragma unroll
    for (int j = 0; j < 4; ++j) {
      short8 bhf = *(const short8*)&sm.ab.Bh[j*16 + l15][lk8];
      short8 blf = *(const short8*)&sm.ab.Bl[j*16 + l15][lk8];
#pragma unroll
      for (int i = 0; i < 3; ++i) {
        acc[i][j] = MFMA16(ah[i], bhf, acc[i][j]);
        acc[i][j] = MFMA16(ah[i], blf, acc[i][j]);
        acc[i][j] = MFMA16(al[i], bhf, acc[i][j]);
      }
    }
  }

  // C -> LDS (union reuse; barrier guarantees MFMA phase done)
  __syncthreads();
#pragma unroll
  for (int i = 0; i < 3; ++i)
#pragma unroll
    for (int j = 0; j < 4; ++j)
#pragma unroll
      for (int q = 0; q < 4; ++q)
        sm.Cs[(3*w + i)*16 + lq*4 + q][j*16 + l15] = acc[i][j][q];
  __syncthreads();

  // epilogue: thread -> (rl = tid>>3, sg = tid&7 -> 4 s values), k = 0..3   [verbatim, validated]
  int rl = tid >> 3;
  int sg = tid & 7;
  int r = r0 + rl;
  float rrt = ws[OFF_RR_T + b*RR + r];
  float rrs = ws[OFF_RR_S + b*RR + r];
  float hhk[4], rhtk[4], rhsk[4], ihr_t[4], ihr_s[4];
#pragma unroll
  for (int k = 0; k < 4; ++k) {
    int idx = (b*RR + r)*KT + k;
    hhk[k]  = ws[OFF_HH + idx];
    rhtk[k] = ws[OFF_RH_T + idx];
    rhsk[k] = ws[OFF_RH_S + idx];
    float nt = sqrtf(fmaxf(hhk[k] - 2.f*rhtk[k] + rrt, 0.f));
    float ns = sqrtf(fmaxf(hhk[k] - 2.f*rhsk[k] + rrs, 0.f));
    ihr_t[k] = 1.f / fmaxf(nt, 1e-8f);
    ihr_s[k] = 1.f / fmaxf(ns, 1e-8f);
  }
  float local = 0.f;
#pragma unroll
  for (int j = 0; j < 4; ++j) {
    int sl2 = sg*4 + j;
    int sidx = (p*BB + b)*SSZ + (s0 + sl2);
    float sst = ws[OFF_SS_T + sidx];
    float sss = ws[OFF_SS_S + sidx];
    float srt = sm.Cs[128 + rl][sl2];
    float srs = sm.Cs[160 + rl][32 + sl2];
    float isr_t = 1.f / fmaxf(sqrtf(fmaxf(sst - 2.f*srt + rrt, 0.f)), 1e-8f);
    float isr_s = 1.f / fmaxf(sqrtf(fmaxf(sss - 2.f*srs + rrs, 0.f)), 1e-8f);
#pragma unroll
    for (int k = 0; k < 4; ++k) {
      float sht = sm.Cs[rl*4 + k][sl2];
      float shs = sm.Cs[rl*4 + k][32 + sl2];
      float ish_t = 1.f / fmaxf(sqrtf(fmaxf(sst - 2.f*sht + hhk[k], 0.f)), 1e-8f);
      float ish_s = 1.f / fmaxf(sqrtf(fmaxf(sss - 2.f*shs + hhk[k], 0.f)), 1e-8f);
      float a1t = (sht - rhtk[k] - srt + rrt) * (isr_t * ihr_t[k]);
      float a2t = (srt - sht - rhtk[k] + hhk[k]) * (ihr_t[k] * ish_t);
      float a3t = (rhtk[k] - srt - sht + sst) * (isr_t * ish_t);
      float a1s = (shs - rhsk[k] - srs + rrs) * (isr_s * ihr_s[k]);
      float a2s = (srs - shs - rhsk[k] + hhk[k]) * (ihr_s[k] * ish_s);
      float a3s = (rhsk[k] - srs - shs + sss) * (isr_s * ish_s);
      local += fabsf(a1s - a1t) + fabsf(a2s - a2t) + fabsf(a3s - a3t);
    }
  }
  float tot = block_sum256(local, sb);
  if (tid == 0) atomicAdd(acc_out, (double)tot);
}

__global__ void k_final(const double* __restrict__ acc, float* __restrict__ out) {
  out[0] = (float)(acc[0] / 3145728.0);   // 3 * B * R * S * K
}

extern "C" void kernel_launch(void* const* d_in, const int* in_sizes, int n_in,
                              void* d_out, int out_size, void* d_ws, size_t ws_size,
                              hipStream_t stream) {
  const float* T  = (const float*)d_in[0];
  const float* Sf = (const float*)d_in[1];
  const int* ref_perm    = (const int*)d_in[2];
  const int* shared_perm = (const int*)d_in[3];
  float* ws = (float*)d_ws;
  double* acc = (double*)(ws + OFF_ACC);

  hipMemsetAsync(acc, 0, sizeof(double), stream);
  k_gather_ref<<<BB*RR, 256, 0, stream>>>(T, Sf, ref_perm, ws);
  k_ne<<<BB*EE, 256, 0, stream>>>(T, ws);
  k_ss<<<NPAIR*BB*SSZ, 256, 0, stream>>>(T, Sf, shared_perm, ws);
  dim3 g1(EE/64, RR/64, BB);
  k_sim<<<g1, 256, 0, stream>>>(T, ws);
  k_topk<<<BB*RR, 256, 0, stream>>>(ws);
  k_gather_high<<<BB*RR*KT, 256, 0, stream>>>(T, Sf, ref_perm, ws);
  dim3 g2(SSZ/32, RR/32, NPAIR*BB);
  k_main<<<g2, 256, 0, stream>>>(T, Sf, shared_perm, ws, acc);
  k_final<<<1, 1, 0, stream>>>(acc, (float*)d_out);
}

// Round 8
// 244.663 us; speedup vs baseline: 2.1295x; 1.0550x over previous
//
#include <hip/hip_runtime.h>
#include <float.h>

#define BB 4
#define PP 1024
#define DD 1024
#define RR 256
#define SSZ 256
#define KT 4
#define EE 4096
#define NPAIR 3

typedef float  f32x4  __attribute__((ext_vector_type(4)));
typedef short  short8 __attribute__((ext_vector_type(8)));

#define MFMA16(a,b,c) __builtin_amdgcn_mfma_f32_16x16x32_bf16((a),(b),(c),0,0,0)

// ---- float-region offsets (in floats) ----
#define OFF_NE    ((size_t)0)         // BB*EE
#define OFF_RR_T  ((size_t)16384)     // BB*RR
#define OFF_RR_S  ((size_t)17408)
#define OFF_HH    ((size_t)18432)     // BB*RR*KT
#define OFF_RH_T  ((size_t)22528)
#define OFF_RH_S  ((size_t)26624)
#define OFF_SS_T  ((size_t)30720)     // NPAIR*BB*SSZ
#define OFF_SS_S  ((size_t)33792)
#define OFF_TOPK  ((size_t)36864)     // BB*RR*KT ints
#define OFF_ACC   ((size_t)40960)     // double (8B aligned)
#define OFF_SIM   ((size_t)45056)     // BB*RR*EE floats (16B aligned)
#define FLOAT_END ((size_t)4239360)   // = OFF_SIM + 4194304

// ---- ushort (bf16) region offsets (in ushorts), base = ws + FLOAT_END ----
#define U_REF_T_HI ((size_t)0)        // BB*RR*DD
#define U_REF_S_HI ((size_t)2097152)
#define U_SIMH_HI  ((size_t)4194304)  // BB*RR*KT*DD
#define REF_DELTA  ((size_t)1048576)  // hi -> lo distance for ref arrays
#define SIMH_DELTA ((size_t)4194304)  // hi -> lo distance for simh
#define U_SH_T_HI  ((size_t)12582912) // NPAIR*BB*SSZ*DD each
#define U_SH_T_LO  ((size_t)15728640)
#define U_SH_S_HI  ((size_t)18874368)
#define U_SH_S_LO  ((size_t)22020096)
// ushort region end = 25165824 (50.3 MB); total ws ~67.3 MB

__device__ inline float block_sum256(float v, float* sb) {
  v += __shfl_down(v, 32); v += __shfl_down(v, 16);
  v += __shfl_down(v, 8);  v += __shfl_down(v, 4);
  v += __shfl_down(v, 2);  v += __shfl_down(v, 1);
  int lane = threadIdx.x & 63, wid = threadIdx.x >> 6;
  if (lane == 0) sb[wid] = v;
  __syncthreads();
  float r = 0.f;
  if (threadIdx.x < 4) r = sb[threadIdx.x];
  r += __shfl_down(r, 2); r += __shfl_down(r, 1);
  __syncthreads();
  return r;   // valid on thread 0
}

__device__ inline float dot4(const float4& a, const float4& b) {
  return a.x*b.x + a.y*b.y + a.z*b.z + a.w*b.w;
}

// round-to-nearest-even split: x = hi + lo (both bf16), |err| ~ 2^-16 |x|
__device__ inline ushort2 bsplit(float x) {
  unsigned u = __float_as_uint(x);
  unsigned hb = (u + 0x7fffu + ((u >> 16) & 1u)) & 0xffff0000u;
  float lo = x - __uint_as_float(hb);
  unsigned ul = __float_as_uint(lo);
  unsigned lb = (ul + 0x7fffu + ((ul >> 16) & 1u)) >> 16;
  return make_ushort2((unsigned short)(hb >> 16), (unsigned short)lb);
}

__device__ inline void split4(float4 f, ushort4& h, ushort4& l) {
  ushort2 t0 = bsplit(f.x), t1 = bsplit(f.y), t2 = bsplit(f.z), t3 = bsplit(f.w);
  h = make_ushort4(t0.x, t1.x, t2.x, t3.x);
  l = make_ushort4(t0.y, t1.y, t2.y, t3.y);
}

__device__ inline void split8(const float* p, uint4& h, uint4& l) {
  float4 f0 = *(const float4*)p;
  float4 f1 = *(const float4*)(p + 4);
  ushort2 t0 = bsplit(f0.x), t1 = bsplit(f0.y), t2 = bsplit(f0.z), t3 = bsplit(f0.w);
  ushort2 t4 = bsplit(f1.x), t5 = bsplit(f1.y), t6 = bsplit(f1.z), t7 = bsplit(f1.w);
  h.x = (unsigned)t0.x | ((unsigned)t1.x << 16); h.y = (unsigned)t2.x | ((unsigned)t3.x << 16);
  h.z = (unsigned)t4.x | ((unsigned)t5.x << 16); h.w = (unsigned)t6.x | ((unsigned)t7.x << 16);
  l.x = (unsigned)t0.y | ((unsigned)t1.y << 16); l.y = (unsigned)t2.y | ((unsigned)t3.y << 16);
  l.z = (unsigned)t4.y | ((unsigned)t5.y << 16); l.w = (unsigned)t6.y | ((unsigned)t7.y << 16);
}

// ---- gather ref rows: norms + bf16 hi/lo split store ----
__global__ __launch_bounds__(256) void k_gather_ref(const float* __restrict__ T,
                                                    const float* __restrict__ Sf,
                                                    const int* __restrict__ ref_perm,
                                                    float* __restrict__ ws) {
  __shared__ float sb[4];
  int b = blockIdx.x >> 8, r = blockIdx.x & 255;
  int pos = ref_perm[r];
  const float4* ts = (const float4*)(T  + ((size_t)(b*8 + 0)*PP + pos)*DD);
  const float4* sv = (const float4*)(Sf + ((size_t)(b*4 + 0)*PP + pos)*DD);
  ushort* uws = (ushort*)(ws + FLOAT_END);
  int t = threadIdx.x;                    // DD/4 == 256
  float4 a = ts[t], c = sv[t];
  size_t base = ((size_t)b*RR + r)*DD + t*4;
  ushort4 h4, l4;
  split4(a, h4, l4);
  *(ushort4*)(uws + U_REF_T_HI + base) = h4;
  *(ushort4*)(uws + U_REF_T_HI + REF_DELTA + base) = l4;
  split4(c, h4, l4);
  *(ushort4*)(uws + U_REF_S_HI + base) = h4;
  *(ushort4*)(uws + U_REF_S_HI + REF_DELTA + base) = l4;
  float r1 = block_sum256(dot4(a, a), sb);
  float r2 = block_sum256(dot4(c, c), sb);
  if (t == 0) {
    ws[OFF_RR_T + b*RR + r] = r1;
    ws[OFF_RR_S + b*RR + r] = r2;
  }
}

// ---- clamped norms of extra_t rows ----
__global__ __launch_bounds__(256) void k_ne(const float* __restrict__ T, float* __restrict__ ws) {
  __shared__ float sb[4];
  int b = blockIdx.x >> 12, e = blockIdx.x & 4095;
  int f = 1 + 2*(e >> 10);
  int pos = e & 1023;
  const float4* src = (const float4*)(T + ((size_t)(b*8 + f)*PP + pos)*DD);
  float4 a = src[threadIdx.x];
  float tot = block_sum256(dot4(a, a), sb);
  if (threadIdx.x == 0) ws[OFF_NE + (size_t)b*EE + e] = fmaxf(sqrtf(tot), 1e-12f);
}

// ---- shared rows: norms + bf16 hi/lo pre-split store (teacher + student) ----
__global__ __launch_bounds__(256) void k_ss(const float* __restrict__ T,
                                            const float* __restrict__ Sf,
                                            const int* __restrict__ shared_perm,
                                            float* __restrict__ ws) {
  __shared__ float sb[4];
  int idx = blockIdx.x;                  // z*SSZ + s, z = p*BB+b
  int p = idx / (BB*SSZ);
  int b = (idx / SSZ) % BB;
  int s = idx % SSZ;
  int pos = shared_perm[s];
  int ti = 2*(p + 1), si = p + 1;
  const float4* tr = (const float4*)(T  + ((size_t)(b*8 + ti)*PP + pos)*DD);
  const float4* sr = (const float4*)(Sf + ((size_t)(b*4 + si)*PP + pos)*DD);
  ushort* uws = (ushort*)(ws + FLOAT_END);
  int t = threadIdx.x;
  float4 a = tr[t], c = sr[t];
  size_t base = (size_t)idx*DD + t*4;
  ushort4 h4, l4;
  split4(a, h4, l4);
  *(ushort4*)(uws + U_SH_T_HI + base) = h4;
  *(ushort4*)(uws + U_SH_T_LO + base) = l4;
  split4(c, h4, l4);
  *(ushort4*)(uws + U_SH_S_HI + base) = h4;
  *(ushort4*)(uws + U_SH_S_LO + base) = l4;
  float r1 = block_sum256(dot4(a, a), sb);
  float r2 = block_sum256(dot4(c, c), sb);
  if (t == 0) { ws[OFF_SS_T + idx] = r1; ws[OFF_SS_S + idx] = r2; }
}

// ---- sim GEMM (MFMA bf16 hi/lo): sim[b,r,e] = dot(ref_t, extra_e)/ne[e] ----
__global__ __launch_bounds__(256) void k_sim(const float* __restrict__ T, float* __restrict__ ws) {
  __shared__ ushort Ah[64][40];
  __shared__ ushort Al[64][40];
  __shared__ ushort Bh[64][40];
  __shared__ ushort Bl[64][40];
  ushort* uws = (ushort*)(ws + FLOAT_END);
  int e0 = blockIdx.x * 64, r0 = blockIdx.y * 64, b = blockIdx.z;
  int tid = threadIdx.x;
  int srow = tid >> 2, sch = tid & 3;
  const ushort* pAh = uws + U_REF_T_HI + ((size_t)(b*RR + r0 + srow))*DD + sch*8;
  int e = e0 + srow;
  const float* pB = T + ((size_t)(b*8 + 1 + 2*(e >> 10))*PP + (e & 1023))*DD + sch*8;
  int w = tid >> 6, l15 = tid & 15, lq = (tid >> 4) & 3, lk8 = lq*8;
  f32x4 acc[4];
#pragma unroll
  for (int j = 0; j < 4; ++j) acc[j] = (f32x4){0.f, 0.f, 0.f, 0.f};

#pragma unroll 1
  for (int k0 = 0; k0 < DD; k0 += 32) {
    uint4 vah = *(const uint4*)(pAh + k0);
    uint4 valo = *(const uint4*)(pAh + REF_DELTA + k0);
    uint4 bhv, blv;
    split8(pB + k0, bhv, blv);
    __syncthreads();
    *(uint4*)&Ah[srow][sch*8] = vah;
    *(uint4*)&Al[srow][sch*8] = valo;
    *(uint4*)&Bh[srow][sch*8] = bhv;
    *(uint4*)&Bl[srow][sch*8] = blv;
    __syncthreads();
    short8 ah = *(const short8*)&Ah[w*16 + l15][lk8];
    short8 al = *(const short8*)&Al[w*16 + l15][lk8];
#pragma unroll
    for (int j = 0; j < 4; ++j) {
      short8 bh = *(const short8*)&Bh[j*16 + l15][lk8];
      short8 bl = *(const short8*)&Bl[j*16 + l15][lk8];
      acc[j] = MFMA16(ah, bh, acc[j]);
      acc[j] = MFMA16(ah, bl, acc[j]);
      acc[j] = MFMA16(al, bh, acc[j]);
    }
  }
#pragma unroll
  for (int j = 0; j < 4; ++j) {
    int ee = e0 + j*16 + l15;
    float inv = 1.f / ws[OFF_NE + (size_t)b*EE + ee];
#pragma unroll
    for (int q = 0; q < 4; ++q) {
      int row = r0 + w*16 + lq*4 + q;
      ws[OFF_SIM + ((size_t)(b*RR + row) << 12) + ee] = acc[j][q] * inv;
    }
  }
}

// ---- top-4 per (b,r), stable (ties -> lower index) ----
__global__ __launch_bounds__(256) void k_topk(float* __restrict__ ws) {
  __shared__ float vals[EE];
  __shared__ float rv[256];
  __shared__ int   ri[256];
  int b = blockIdx.x >> 8, r = blockIdx.x & 255;
  const float* srow = ws + OFF_SIM + ((size_t)(b*RR + r))*EE;
  int tid = threadIdx.x;
#pragma unroll
  for (int i = 0; i < 16; ++i) vals[i*256 + tid] = srow[i*256 + tid];
  __syncthreads();
  int* outi = (int*)(ws + OFF_TOPK) + ((size_t)(b*RR + r))*KT;
  for (int k = 0; k < KT; ++k) {
    float bv = -FLT_MAX; int bi = 0x7fffffff;
#pragma unroll
    for (int i = 0; i < 16; ++i) {
      int e = i*256 + tid;
      float v = vals[e];
      if (v > bv || (v == bv && e < bi)) { bv = v; bi = e; }
    }
    rv[tid] = bv; ri[tid] = bi;
    __syncthreads();
    for (int off = 128; off > 0; off >>= 1) {
      if (tid < off) {
        float v2 = rv[tid+off]; int i2 = ri[tid+off];
        if (v2 > rv[tid] || (v2 == rv[tid] && i2 < ri[tid])) { rv[tid] = v2; ri[tid] = i2; }
      }
      __syncthreads();
    }
    if (tid == 0) { outi[k] = ri[0]; vals[ri[0]] = -FLT_MAX; }
    __syncthreads();
  }
}

// ---- gather selected rows: bf16 hi/lo store + hh / rh_t / rh_s (fp32) ----
__global__ __launch_bounds__(256) void k_gather_high(const float* __restrict__ T,
                                                     const float* __restrict__ Sf,
                                                     const int* __restrict__ ref_perm,
                                                     float* __restrict__ ws) {
  __shared__ float sb[4];
  int idx = blockIdx.x;                        // (b*RR + r)*KT + k
  int e = ((const int*)(ws + OFF_TOPK))[idx];
  int b = idx >> 10;
  int r = (idx >> 2) & 255;
  int rpos = ref_perm[r];
  const float4* src = (const float4*)(T + ((size_t)(b*8 + 1 + 2*(e >> 10))*PP + (e & 1023))*DD);
  const float4* rt  = (const float4*)(T  + ((size_t)(b*8 + 0)*PP + rpos)*DD);
  const float4* rs  = (const float4*)(Sf + ((size_t)(b*4 + 0)*PP + rpos)*DD);
  ushort* uws = (ushort*)(ws + FLOAT_END);
  int t = threadIdx.x;
  float4 h = src[t];
  ushort4 h4, l4;
  split4(h, h4, l4);
  *(ushort4*)(uws + U_SIMH_HI + (size_t)idx*DD + t*4) = h4;
  *(ushort4*)(uws + U_SIMH_HI + SIMH_DELTA + (size_t)idx*DD + t*4) = l4;
  float4 a = rt[t], c = rs[t];
  float r1 = block_sum256(dot4(h, h), sb);
  float r2 = block_sum256(dot4(h, a), sb);
  float r3 = block_sum256(dot4(h, c), sb);
  if (t == 0) { ws[OFF_HH + idx] = r1; ws[OFF_RH_T + idx] = r2; ws[OFF_RH_S + idx] = r3; }
}

// ---- main fused kernel: all-bf16 staging, transposed write map, XCD-grouped ----
// A rows (192): [0..127] sim_high, [128..159] ref_t, [160..191] ref_s
// B rows (64):  [0..31] sh_t(s0+sl), [32..63] sh_s(s0+sl).  BK=32.
// Block map: d = q*24 + u; u -> (z, r-half) pinned to XCD u%8; q -> (r_loc, s_t).
__global__ __launch_bounds__(256) void k_main(float* __restrict__ ws,
                                              double* __restrict__ acc_out) {
  __shared__ union SM {
    struct { ushort Ah[192][40]; ushort Al[192][40]; ushort Bh[64][40]; ushort Bl[64][40]; } ab;
    float Cs[192][65];
  } sm;
  __shared__ float sb[4];
  const ushort* uws = (const ushort*)(ws + FLOAT_END);

  int d = blockIdx.x;
  int u = d % 24, q = d / 24;
  int z = u >> 1;
  int r_t = (u & 1)*4 + (q >> 3);
  int s_t = q & 7;
  int p = z >> 2, b = z & 3;
  int s0 = s_t*32, r0 = r_t*32;
  int tid = threadIdx.x;
  int w = tid >> 6;
  int l15 = tid & 15, lq = (tid >> 4) & 3;

  // staging: 32 groups of 16 rows (hi/lo x A/B); wave w owns G = 8w..8w+7.
  // lane l: row = l&15 (bank-clean on 80-B stride), chunk = (l>>4)&3.
  const ushort* gsrc[8];
  int gdst[8];
  {
    size_t flat0 = ((size_t)(b*RR + r0)) * 4;     // simh flat row base
    size_t ref0  = (size_t)(b*RR + r0);
    size_t sh0   = (size_t)(z*SSZ + s0);
    size_t laneoff = (size_t)l15*DD + lq*8;
#pragma unroll
    for (int i = 0; i < 8; ++i) {
      int G = 8*w + i;
      const ushort* s; int dofs;
      if (G < 12) {                                // Ah rows G*16
        int gr = G*16;
        if (G < 8)       s = uws + U_SIMH_HI + (flat0 + gr)*DD;
        else if (G < 10) s = uws + U_REF_T_HI + (ref0 + (gr-128))*DD;
        else             s = uws + U_REF_S_HI + (ref0 + (gr-160))*DD;
        dofs = gr*40;
      } else if (G < 24) {                         // Al rows (G-12)*16
        int gr = (G-12)*16;
        if (G < 20)      s = uws + U_SIMH_HI + SIMH_DELTA + (flat0 + gr)*DD;
        else if (G < 22) s = uws + U_REF_T_HI + REF_DELTA + (ref0 + (gr-128))*DD;
        else             s = uws + U_REF_S_HI + REF_DELTA + (ref0 + (gr-160))*DD;
        dofs = 192*40 + gr*40;
      } else if (G < 28) {                         // Bh rows (G-24)*16
        int gr = (G-24)*16;
        if (G < 26)      s = uws + U_SH_T_HI + (sh0 + gr)*DD;
        else             s = uws + U_SH_S_HI + (sh0 + (gr-32))*DD;
        dofs = 384*40 + gr*40;
      } else {                                     // Bl rows (G-28)*16
        int gr = (G-28)*16;
        if (G < 30)      s = uws + U_SH_T_LO + (sh0 + gr)*DD;
        else             s = uws + U_SH_S_LO + (sh0 + (gr-32))*DD;
        dofs = 448*40 + gr*40;
      }
      gsrc[i] = s + laneoff;
      gdst[i] = dofs + l15*40 + lq*8;
    }
  }
  ushort* lds = &sm.ab.Ah[0][0];

  f32x4 acc[3][4];
#pragma unroll
  for (int i = 0; i < 3; ++i)
#pragma unroll
    for (int j = 0; j < 4; ++j) acc[i][j] = (f32x4){0.f, 0.f, 0.f, 0.f};

#pragma unroll 1
  for (int k0 = 0; k0 < DD; k0 += 32) {
    uint4 v0 = *(const uint4*)(gsrc[0] + k0);
    uint4 v1 = *(const uint4*)(gsrc[1] + k0);
    uint4 v2 = *(const uint4*)(gsrc[2] + k0);
    uint4 v3 = *(const uint4*)(gsrc[3] + k0);
    uint4 v4 = *(const uint4*)(gsrc[4] + k0);
    uint4 v5 = *(const uint4*)(gsrc[5] + k0);
    uint4 v6 = *(const uint4*)(gsrc[6] + k0);
    uint4 v7 = *(const uint4*)(gsrc[7] + k0);
    __syncthreads();                      // prev-iter reads done
    *(uint4*)(lds + gdst[0]) = v0;
    *(uint4*)(lds + gdst[1]) = v1;
    *(uint4*)(lds + gdst[2]) = v2;
    *(uint4*)(lds + gdst[3]) = v3;
    *(uint4*)(lds + gdst[4]) = v4;
    *(uint4*)(lds + gdst[5]) = v5;
    *(uint4*)(lds + gdst[6]) = v6;
    *(uint4*)(lds + gdst[7]) = v7;
    __syncthreads();                      // tile ready
    short8 ah[3], al[3];
#pragma unroll
    for (int i = 0; i < 3; ++i) {
      ah[i] = *(const short8*)&sm.ab.Ah[(3*w + i)*16 + l15][lq*8];
      al[i] = *(const short8*)&sm.ab.Al[(3*w + i)*16 + l15][lq*8];
    }
#pragma unroll
    for (int j = 0; j < 4; ++j) {
      short8 bhf = *(const short8*)&sm.ab.Bh[j*16 + l15][lq*8];
      short8 blf = *(const short8*)&sm.ab.Bl[j*16 + l15][lq*8];
#pragma unroll
      for (int i = 0; i < 3; ++i) {
        acc[i][j] = MFMA16(ah[i], bhf, acc[i][j]);
        acc[i][j] = MFMA16(ah[i], blf, acc[i][j]);
        acc[i][j] = MFMA16(al[i], bhf, acc[i][j]);
      }
    }
  }

  // C -> LDS (union reuse)
  __syncthreads();
#pragma unroll
  for (int i = 0; i < 3; ++i)
#pragma unroll
    for (int j = 0; j < 4; ++j)
#pragma unroll
      for (int qq = 0; qq < 4; ++qq)
        sm.Cs[(3*w + i)*16 + lq*4 + qq][j*16 + l15] = acc[i][j][qq];
  __syncthreads();

  // epilogue (validated, verbatim structure)
  int rl = tid >> 3;
  int sg = tid & 7;
  int r = r0 + rl;
  float rrt = ws[OFF_RR_T + b*RR + r];
  float rrs = ws[OFF_RR_S + b*RR + r];
  float hhk[4], rhtk[4], rhsk[4], ihr_t[4], ihr_s[4];
#pragma unroll
  for (int k = 0; k < 4; ++k) {
    int idx = (b*RR + r)*KT + k;
    hhk[k]  = ws[OFF_HH + idx];
    rhtk[k] = ws[OFF_RH_T + idx];
    rhsk[k] = ws[OFF_RH_S + idx];
    float nt = sqrtf(fmaxf(hhk[k] - 2.f*rhtk[k] + rrt, 0.f));
    float ns = sqrtf(fmaxf(hhk[k] - 2.f*rhsk[k] + rrs, 0.f));
    ihr_t[k] = 1.f / fmaxf(nt, 1e-8f);
    ihr_s[k] = 1.f / fmaxf(ns, 1e-8f);
  }
  float local = 0.f;
#pragma unroll
  for (int j = 0; j < 4; ++j) {
    int sl2 = sg*4 + j;
    int sidx = z*SSZ + (s0 + sl2);
    float sst = ws[OFF_SS_T + sidx];
    float sss = ws[OFF_SS_S + sidx];
    float srt = sm.Cs[128 + rl][sl2];
    float srs = sm.Cs[160 + rl][32 + sl2];
    float isr_t = 1.f / fmaxf(sqrtf(fmaxf(sst - 2.f*srt + rrt, 0.f)), 1e-8f);
    float isr_s = 1.f / fmaxf(sqrtf(fmaxf(sss - 2.f*srs + rrs, 0.f)), 1e-8f);
#pragma unroll
    for (int k = 0; k < 4; ++k) {
      float sht = sm.Cs[rl*4 + k][sl2];
      float shs = sm.Cs[rl*4 + k][32 + sl2];
      float ish_t = 1.f / fmaxf(sqrtf(fmaxf(sst - 2.f*sht + hhk[k], 0.f)), 1e-8f);
      float ish_s = 1.f / fmaxf(sqrtf(fmaxf(sss - 2.f*shs + hhk[k], 0.f)), 1e-8f);
      float a1t = (sht - rhtk[k] - srt + rrt) * (isr_t * ihr_t[k]);
      float a2t = (srt - sht - rhtk[k] + hhk[k]) * (ihr_t[k] * ish_t);
      float a3t = (rhtk[k] - srt - sht + sst) * (isr_t * ish_t);
      float a1s = (shs - rhsk[k] - srs + rrs) * (isr_s * ihr_s[k]);
      float a2s = (srs - shs - rhsk[k] + hhk[k]) * (ihr_s[k] * ish_s);
      float a3s = (rhsk[k] - srs - shs + sss) * (isr_s * ish_s);
      local += fabsf(a1s - a1t) + fabsf(a2s - a2t) + fabsf(a3s - a3t);
    }
  }
  float tot = block_sum256(local, sb);
  if (tid == 0) atomicAdd(acc_out, (double)tot);
}

__global__ void k_final(const double* __restrict__ acc, float* __restrict__ out) {
  out[0] = (float)(acc[0] / 3145728.0);   // 3 * B * R * S * K
}

extern "C" void kernel_launch(void* const* d_in, const int* in_sizes, int n_in,
                              void* d_out, int out_size, void* d_ws, size_t ws_size,
                              hipStream_t stream) {
  const float* T  = (const float*)d_in[0];
  const float* Sf = (const float*)d_in[1];
  const int* ref_perm    = (const int*)d_in[2];
  const int* shared_perm = (const int*)d_in[3];
  float* ws = (float*)d_ws;
  double* acc = (double*)(ws + OFF_ACC);

  hipMemsetAsync(acc, 0, sizeof(double), stream);
  k_gather_ref<<<BB*RR, 256, 0, stream>>>(T, Sf, ref_perm, ws);
  k_ne<<<BB*EE, 256, 0, stream>>>(T, ws);
  k_ss<<<NPAIR*BB*SSZ, 256, 0, stream>>>(T, Sf, shared_perm, ws);
  dim3 g1(EE/64, RR/64, BB);
  k_sim<<<g1, 256, 0, stream>>>(T, ws);
  k_topk<<<BB*RR, 256, 0, stream>>>(ws);
  k_gather_high<<<BB*RR*KT, 256, 0, stream>>>(T, Sf, ref_perm, ws);
  k_main<<<768, 256, 0, stream>>>(ws, acc);
  k_final<<<1, 1, 0, stream>>>(acc, (float*)d_out);
}